// Round 5
// baseline (3626.026 us; speedup 1.0000x reference)
//
#include <hip/hip_runtime.h>

// Bit-exact gold model (VERIFIED rounds 12-13, absmax=0): per C element the
// GEMM is 4 panels of 512 sequential fmaf's (k ascending, single acc); panel
// sums folded ((p0+p1)+p2)+p3; then bias add; elementwise = one rounded fp32
// op per ufunc, contract(off).
// Round 19 (= round 18 resubmit, infra failure x2): LDS-free GEMM.
// Cost model from rounds 14-17: per-CU LDS ~85 B/cyc caps any LDS-fed fp32
// microtile at <=67% VALU; s_load A unpipelineable (SMEM out-of-order ->
// lgkmcnt(0) drain); 1-kk B lookahead stalls on L2 latency. Fix: A
// wave-broadcast (8 shared rows, uniform-addr VGPR loads via opaque-zero;
// ~0 B/lane-FMA), B per-lane from L2 (m=8 -> 0.5 B/lane-FMA = 64 B/cyc/CU
// ~ L2 rate), 2-slot register pipeline at 4-kk granularity (lead ~256 cyc
// > L2 latency). TM=8 x TN=256, 1-wave blocks, grid (8,64,4)=2048 ->
// 2 waves/SIMD, no barriers, no LDS. grid.x = n-slice = XCD -> per-XCD B
// working set 2 MB, L2-resident.

#pragma clang fp contract(off)

#define B_ROWS 512
#define N_OUT 2048
#define K_IN 2048
#define NSTEP 16
#define NPANEL 4
#define PANK 512
#define TMG 8
#define TNG 256
#define NGRP (PANK / 4)   // 128 groups of 4 k each

// ---- 32x32 LDS-tiled transpose: WT[k][n] = W[n][k] (*mask) ----
__global__ __launch_bounds__(256) void transpose_tile(
    const float* __restrict__ W, const int* __restrict__ mask,
    float* __restrict__ WT, int useMask)
{
    __shared__ float t[32][33];
    int kb = blockIdx.x * 32, nb = blockIdx.y * 32;
    int tx = threadIdx.x, ty = threadIdx.y;   // block (32, 8)
#pragma unroll
    for (int r = 0; r < 32; r += 8) {
        size_t src = (size_t)(nb + ty + r) * K_IN + (kb + tx);
        float v = W[src];
        if (useMask) v *= (float)mask[src];   // mask in {0,1}: exact
        t[ty + r][tx] = v;
    }
    __syncthreads();
#pragma unroll
    for (int r = 0; r < 32; r += 8)
        WT[(size_t)(kb + ty + r) * N_OUT + (nb + tx)] = t[tx][ty + r];
}

__global__ __launch_bounds__(256) void init_state(float* mem, float* ath,
                                                  float* ssum, float* spk) {
    int idx = blockIdx.x * 256 + threadIdx.x;
    mem[idx] = 0.0f; ath[idx] = 0.0f; ssum[idx] = 0.0f; spk[idx] = 0.0f;
}

// ---- one K-panel of C = A @ BT : Cp[panel][m][n], bit-exact 512-chain ----
// One wave per block. A: 8 rows shared by all lanes (uniform-address vector
// loads, forced to VGPR path via opaque zero). B: per-lane float4 column
// slice from L2. 2-slot register pipeline over 128 groups of 4 k.
__global__ __launch_bounds__(64, 2) void gemm_panel(
    const float* __restrict__ A,    // [512][2048] (x or spk)
    const float* __restrict__ BT,   // [2048][2048] (WT)
    float* __restrict__ Cp)         // [4][512][2048]
{
    const int lane = threadIdx.x;
    const int n0 = blockIdx.x * TNG;
    const int m0 = blockIdx.y * TMG;
    const int pan = blockIdx.z;
    const int kbase = pan * PANK;

    // opaque zero in a VGPR: keeps A addresses formally lane-dependent so the
    // compiler emits global_load (pipelineable, vmcnt) instead of s_load
    // (SMEM is out-of-order -> lgkmcnt(0) drain, round-16 failure mode).
    unsigned vzero;
    asm volatile("v_mov_b32 %0, 0" : "=v"(vzero));

    float acc[TMG][4];
#pragma unroll
    for (int r = 0; r < TMG; r++)
#pragma unroll
        for (int j = 0; j < 4; j++) acc[r][j] = 0.0f;

    const float* Abase = A + (size_t)m0 * K_IN + kbase + (size_t)vzero;
    const float* Bbase = BT + (size_t)kbase * N_OUT + n0 + lane * 4;

    float4 a0[TMG], a1[TMG], b0[4], b1[4];

#define LOAD_A(dst, g)                                                      \
    {                                                                       \
        _Pragma("unroll")                                                   \
        for (int r = 0; r < TMG; r++)                                       \
            dst[r] = *(const float4*)(Abase + (size_t)r * K_IN + (g) * 4);  \
    }
#define LOAD_B(dst, g)                                                      \
    {                                                                       \
        _Pragma("unroll")                                                   \
        for (int q = 0; q < 4; q++)                                         \
            dst[q] = *(const float4*)(Bbase + (size_t)((g) * 4 + q) * N_OUT); \
    }
    // q ascending inside, groups ascending outside => each acc element's
    // 512-chain is k-ascending with a single accumulator: gold order.
#define COMPUTE(Aq, Bq)                                                     \
    {                                                                       \
        _Pragma("unroll")                                                   \
        for (int q = 0; q < 4; q++) {                                       \
            float bb[4] = {Bq[q].x, Bq[q].y, Bq[q].z, Bq[q].w};             \
            _Pragma("unroll")                                               \
            for (int r = 0; r < TMG; r++) {                                 \
                float av = (q == 0) ? Aq[r].x : (q == 1) ? Aq[r].y          \
                         : (q == 2) ? Aq[r].z : Aq[r].w;                    \
                _Pragma("unroll")                                           \
                for (int j = 0; j < 4; j++)                                 \
                    acc[r][j] = fmaf(av, bb[j], acc[r][j]);                 \
            }                                                               \
        }                                                                   \
    }

    LOAD_A(a0, 0); LOAD_B(b0, 0);
    LOAD_A(a1, 1); LOAD_B(b1, 1);
    for (int g = 0; g < NGRP; g += 2) {
        const int gp = (g + 2) & (NGRP - 1);   // wraps at end: dead loads, in-bounds
        const int gq = (g + 3) & (NGRP - 1);
        COMPUTE(a0, b0);
        LOAD_A(a0, gp); LOAD_B(b0, gp);        // prefetch g+2 (lead ~1 group)
        COMPUTE(a1, b1);
        LOAD_A(a1, gq); LOAD_B(b1, gq);        // prefetch g+3
    }

    const size_t P = (size_t)B_ROWS * N_OUT;
#pragma unroll
    for (int r = 0; r < TMG; r++) {
        size_t off = (size_t)pan * P + (size_t)(m0 + r) * N_OUT + n0 + lane * 4;
        *(float4*)(Cp + off) = make_float4(acc[r][0], acc[r][1], acc[r][2], acc[r][3]);
    }
#undef LOAD_A
#undef LOAD_B
#undef COMPUTE
}

// ---- ff = fold(Cp) + b_fc  (bit-exact ordered fold) ----
__global__ __launch_bounds__(256) void ff_fold(
    const float* __restrict__ Cp, const float* __restrict__ b_fc,
    float* __restrict__ ff)
{
    const size_t P = (size_t)B_ROWS * N_OUT;
    size_t base = ((size_t)blockIdx.x * 256 + threadIdx.x) * 4;
    int n = (int)(base & (N_OUT - 1));
    float4 p0 = *(const float4*)(Cp + base);
    float4 p1 = *(const float4*)(Cp + P + base);
    float4 p2 = *(const float4*)(Cp + 2 * P + base);
    float4 p3 = *(const float4*)(Cp + 3 * P + base);
    float4 bv = *(const float4*)(b_fc + n);
    float4 o;
    o.x = (((p0.x + p1.x) + p2.x) + p3.x) + bv.x;
    o.y = (((p0.y + p1.y) + p2.y) + p3.y) + bv.y;
    o.z = (((p0.z + p1.z) + p2.z) + p3.z) + bv.z;
    o.w = (((p0.w + p1.w) + p2.w) + p3.w) + bv.w;
    *(float4*)(ff + base) = o;
}

// ---- fold(Cp) + b_rec -> memr, then fused fp32 SNN elementwise update ----
__global__ __launch_bounds__(256) void fold_update(
    const float* __restrict__ Cp, const float* __restrict__ b_rec,
    const float* __restrict__ spk_in, const float* __restrict__ ff,
    float* __restrict__ mem, float* __restrict__ ath,
    float* __restrict__ ssum, float* __restrict__ spk_out,
    float* __restrict__ out, int last)
{
    const size_t P = (size_t)B_ROWS * N_OUT;
    size_t base = ((size_t)blockIdx.x * 256 + threadIdx.x) * 4;
    int n = (int)(base & (N_OUT - 1));
    float4 p0 = *(const float4*)(Cp + base);
    float4 p1 = *(const float4*)(Cp + P + base);
    float4 p2 = *(const float4*)(Cp + 2 * P + base);
    float4 p3 = *(const float4*)(Cp + 3 * P + base);
    float4 bv = *(const float4*)(b_rec + n);
    float4 sv = *(const float4*)(spk_in + base);
    float4 av = *(const float4*)(ath + base);
    float4 mv = *(const float4*)(mem + base);
    float4 fv = *(const float4*)(ff + base);
    float4 uv = *(const float4*)(ssum + base);

    float cr[4] = {(((p0.x + p1.x) + p2.x) + p3.x),
                   (((p0.y + p1.y) + p2.y) + p3.y),
                   (((p0.z + p1.z) + p2.z) + p3.z),
                   (((p0.w + p1.w) + p2.w) + p3.w)};
    float ba[4] = {bv.x, bv.y, bv.z, bv.w};
    float sa[4] = {sv.x, sv.y, sv.z, sv.w};
    float aa[4] = {av.x, av.y, av.z, av.w};
    float ma[4] = {mv.x, mv.y, mv.z, mv.w};
    float fa[4] = {fv.x, fv.y, fv.z, fv.w};
    float ua[4] = {uv.x, uv.y, uv.z, uv.w};
    float mo[4], ao[4], uo[4], so[4];
#pragma unroll
    for (int j = 0; j < 4; j++) {
        float memr  = cr[j] + ba[j];      // rounded add
        float sp    = sa[j];
        float t1    = aa[j] * 0.9f;       // rounded
        float t2    = 0.5f * sp;          // exact
        float athn  = t1 + t2;            // rounded
        float u1    = ma[j] * 0.2f;       // rounded
        float u2    = 1.0f - sp;          // exact {1,0,-1}
        float u3    = u1 * u2;            // exact (sign/zero)
        float u4    = u3 + fa[j];         // rounded
        float u5    = athn * 0.2f;        // rounded
        float memff = u4 - u5;            // rounded
        float s_ff  = (memff > 0.5f) ? 1.0f : 0.0f;
        float s_r   = (memr  > 0.5f) ? 1.0f : 0.0f;
        mo[j] = memff + memr;             // rounded
        ao[j] = athn;
        so[j] = s_ff + s_r;               // exact
        uo[j] = ua[j] + so[j];            // exact (small ints)
    }
    *(float4*)(mem + base)     = make_float4(mo[0], mo[1], mo[2], mo[3]);
    *(float4*)(ath + base)     = make_float4(ao[0], ao[1], ao[2], ao[3]);
    *(float4*)(ssum + base)    = make_float4(uo[0], uo[1], uo[2], uo[3]);
    *(float4*)(spk_out + base) = make_float4(so[0], so[1], so[2], so[3]);
    if (last)
        *(float4*)(out + base) = make_float4(uo[0], uo[1], uo[2], uo[3]);
}

extern "C" void kernel_launch(void* const* d_in, const int* in_sizes, int n_in,
                              void* d_out, int out_size, void* d_ws, size_t ws_size,
                              hipStream_t stream) {
    const float* x      = (const float*)d_in[0];
    const float* W_fc   = (const float*)d_in[1];
    const float* b_fc   = (const float*)d_in[2];
    const float* W_rec  = (const float*)d_in[3];
    const float* b_rec  = (const float*)d_in[4];
    const int*   rmask  = (const int*)d_in[5];
    // d_in[6] = spike_window (16)

    char* ws = (char*)d_ws;
    float* WT   = (float*)(ws);                    // 16 MB (fc, then rec)
    float* ff   = (float*)(ws + (16u << 20));      //  4 MB
    float* mem  = (float*)(ws + (20u << 20));      //  4 MB
    float* ath  = (float*)(ws + (24u << 20));      //  4 MB
    float* ssum = (float*)(ws + (28u << 20));      //  4 MB
    float* spkA = (float*)(ws + (32u << 20));      //  4 MB
    float* spkB = (float*)(ws + (36u << 20));      //  4 MB
    float* Cp   = (float*)(ws + (40u << 20));      // 16 MB (total 56 MB)

    dim3 gridT(K_IN / 32, N_OUT / 32);             // (64, 64)
    dim3 blkT(32, 8);
    dim3 gridS((B_ROWS * N_OUT) / 256);            // 4096
    dim3 gridG(N_OUT / TNG, B_ROWS / TMG, NPANEL); // (8, 64, 4) = 2048 blocks
    dim3 gridF((B_ROWS * N_OUT) / (256 * 4));      // 1024

    transpose_tile<<<gridT, blkT, 0, stream>>>(W_fc, rmask, WT, 0);
    init_state<<<gridS, 256, 0, stream>>>(mem, ath, ssum, spkA);
    gemm_panel<<<gridG, 64, 0, stream>>>(x, WT, Cp);
    ff_fold<<<gridF, 256, 0, stream>>>(Cp, b_fc, ff);
    transpose_tile<<<gridT, blkT, 0, stream>>>(W_rec, rmask, WT, 1);

    for (int t = 0; t < NSTEP; t++) {
        const float* si = (t & 1) ? spkB : spkA;
        float*       so = (t & 1) ? spkA : spkB;
        gemm_panel<<<gridG, 64, 0, stream>>>(si, WT, Cp);
        fold_update<<<gridF, 256, 0, stream>>>(
            Cp, b_rec, si, ff, mem, ath, ssum, so, (float*)d_out, t == NSTEP - 1);
    }
}

// Round 6
// 1538.810 us; speedup vs baseline: 2.3564x; 2.3564x over previous
//
#include <hip/hip_runtime.h>

// Bit-exact gold model (VERIFIED rounds 12-13, absmax=0): per C element the
// GEMM is 4 panels of 512 sequential fmaf's (k ascending, single acc); panel
// sums folded ((p0+p1)+p2)+p3; then bias add; elementwise = one rounded fp32
// op per ufunc, contract(off).
// Round 20: broadcast-A LDS GEMM. Cost model (rounds 14-19): LDS pipe ~85
// B/cyc vs VALU 128 lane-FMA/cyc; 8x8 microtile = 1 B/FMA -> 67% cap;
// global-fed designs die on L2 latency (compiler re-sinks reg prefetch);
// s_load unpipelineable. Fix: per-wave 16m x (64 lanes x 4n) microtile ->
// B = 0.25 B/lane-FMA (1 conflict-free b128/lane/kk), A wave-uniform
// broadcast reads (~free), staging via global_load_lds DMA (no LDS-write
// instrs, no VGPR round-trip). 4-wave blocks share [16x256] B + [16x64] A
// tiles (40 KB), grid (8,8,4)=256 = 1 block/CU, one __syncthreads per kt
// (its vmcnt(0) drains DMA issued a full kt earlier -> no stall).
// bid%8 = n-tile = XCD -> B slab 2 MB/XCD, L2-resident.

#pragma clang fp contract(off)

#define B_ROWS 512
#define N_OUT 2048
#define K_IN 2048
#define NSTEP 16
#define NPANEL 4
#define PANK 512
#define BKT 16                 // k per tile
#define BTM 64                 // block m rows (4 waves x 16)
#define BTN 256                // block n cols (64 lanes x 4)
#define WTM 16                 // rows per wave
#define NJ 4                   // cols per lane
#define NTILES (PANK / BKT)    // 32

typedef const __attribute__((address_space(1))) void* gptr_t;
typedef __attribute__((address_space(3))) void* lptr_t;

// ---- 32x32 LDS-tiled transpose: WT[k][n] = W[n][k] (*mask) ----
__global__ __launch_bounds__(256) void transpose_tile(
    const float* __restrict__ W, const int* __restrict__ mask,
    float* __restrict__ WT, int useMask)
{
    __shared__ float t[32][33];
    int kb = blockIdx.x * 32, nb = blockIdx.y * 32;
    int tx = threadIdx.x, ty = threadIdx.y;   // block (32, 8)
#pragma unroll
    for (int r = 0; r < 32; r += 8) {
        size_t src = (size_t)(nb + ty + r) * K_IN + (kb + tx);
        float v = W[src];
        if (useMask) v *= (float)mask[src];   // mask in {0,1}: exact
        t[ty + r][tx] = v;
    }
    __syncthreads();
#pragma unroll
    for (int r = 0; r < 32; r += 8)
        WT[(size_t)(kb + ty + r) * N_OUT + (nb + tx)] = t[tx][ty + r];
}

__global__ __launch_bounds__(256) void init_state(float* mem, float* ath,
                                                  float* ssum, float* spk) {
    int idx = blockIdx.x * 256 + threadIdx.x;
    mem[idx] = 0.0f; ath[idx] = 0.0f; ssum[idx] = 0.0f; spk[idx] = 0.0f;
}

// ---- one K-panel of C = A @ BT : Cp[panel][m][n], bit-exact 512-chain ----
// 4 waves/block. Wave w owns rows m0+w*16..+15 (A broadcast-read: all lanes
// same address). Lane owns cols n0+lane*4..+3 (one b128/kk, conflict-free).
__global__ __launch_bounds__(256, 1) void gemm_panel(
    const float* __restrict__ A,    // [512][2048] (x or spk)
    const float* __restrict__ BT,   // [2048][2048] (WT)
    float* __restrict__ Cp)         // [4][512][2048]
{
    __shared__ float Bs[2][BKT][BTN];   // 32 KB
    __shared__ float As[2][BKT][BTM];   //  8 KB
    const int tid  = threadIdx.x;
    const int w    = tid >> 6;          // wave 0..3
    const int lane = tid & 63;
    const int n0 = blockIdx.x * BTN;
    const int m0 = blockIdx.y * BTM;
    const int pan = blockIdx.z;
    const int kbase = pan * PANK;

    float acc[WTM][NJ];
#pragma unroll
    for (int m = 0; m < WTM; m++)
#pragma unroll
        for (int j = 0; j < NJ; j++) acc[m][j] = 0.0f;

    // stage(buf, kt): wave w DMAs rows w*4+i of both tiles.
    //  B row: 64 lanes x 16 B = 1024 B = one [256n] row (LDS linear dest).
    //  A row: 64 lanes x 4 B  =  256 B = one [64m] row; global src is a
    //  stride-K_IN gather (per-lane addr ok); sectors L1-reused across the
    //  16 rows of the kt -> no overfetch.
    auto stage = [&](int buf, int kt) {
#pragma unroll
        for (int i = 0; i < 4; i++) {
            const int row = w * 4 + i;
            __builtin_amdgcn_global_load_lds(
                (gptr_t)(uintptr_t)(BT + (size_t)(kbase + kt * BKT + row) * N_OUT
                                        + n0 + lane * 4),
                (lptr_t)(uintptr_t)&Bs[buf][row][0], 16, 0, 0);
            __builtin_amdgcn_global_load_lds(
                (gptr_t)(uintptr_t)(A + (size_t)(m0 + lane) * K_IN
                                       + kbase + kt * BKT + row),
                (lptr_t)(uintptr_t)&As[buf][row][0], 4, 0, 0);
        }
    };

    stage(0, 0);
    for (int kt = 0; kt < NTILES; kt++) {
        const int buf = kt & 1;
        // syncthreads emits s_waitcnt vmcnt(0) lgkmcnt(0) + s_barrier:
        // (a) this wave's DMAs for buf (issued a full kt ago) are done;
        // (b) barrier => ALL waves' DMAs done and all waves finished
        //     reading buf^1 (their kt-1 compute precedes this point).
        __syncthreads();
        if (kt + 1 < NTILES) stage(buf ^ 1, kt + 1);  // flies during compute
#pragma unroll
        for (int kk = 0; kk < BKT; kk++) {
            float4 b4  = *(const float4*)&Bs[buf][kk][lane * 4];
            float4 am0 = *(const float4*)&As[buf][kk][w * WTM + 0];
            float4 am1 = *(const float4*)&As[buf][kk][w * WTM + 4];
            float4 am2 = *(const float4*)&As[buf][kk][w * WTM + 8];
            float4 am3 = *(const float4*)&As[buf][kk][w * WTM + 12];
            float a[WTM] = {am0.x, am0.y, am0.z, am0.w,
                            am1.x, am1.y, am1.z, am1.w,
                            am2.x, am2.y, am2.z, am2.w,
                            am3.x, am3.y, am3.z, am3.w};
            float b[NJ] = {b4.x, b4.y, b4.z, b4.w};
            // kt asc, kk asc, single accumulator => gold 512-chain order
#pragma unroll
            for (int m = 0; m < WTM; m++)
#pragma unroll
                for (int j = 0; j < NJ; j++)
                    acc[m][j] = fmaf(a[m], b[j], acc[m][j]);
        }
    }

    const size_t P = (size_t)B_ROWS * N_OUT;
#pragma unroll
    for (int m = 0; m < WTM; m++) {
        size_t off = (size_t)pan * P
                   + (size_t)(m0 + w * WTM + m) * N_OUT + n0 + lane * NJ;
        *(float4*)(Cp + off) = make_float4(acc[m][0], acc[m][1], acc[m][2], acc[m][3]);
    }
}

// ---- ff = fold(Cp) + b_fc  (bit-exact ordered fold) ----
__global__ __launch_bounds__(256) void ff_fold(
    const float* __restrict__ Cp, const float* __restrict__ b_fc,
    float* __restrict__ ff)
{
    const size_t P = (size_t)B_ROWS * N_OUT;
    size_t base = ((size_t)blockIdx.x * 256 + threadIdx.x) * 4;
    int n = (int)(base & (N_OUT - 1));
    float4 p0 = *(const float4*)(Cp + base);
    float4 p1 = *(const float4*)(Cp + P + base);
    float4 p2 = *(const float4*)(Cp + 2 * P + base);
    float4 p3 = *(const float4*)(Cp + 3 * P + base);
    float4 bv = *(const float4*)(b_fc + n);
    float4 o;
    o.x = (((p0.x + p1.x) + p2.x) + p3.x) + bv.x;
    o.y = (((p0.y + p1.y) + p2.y) + p3.y) + bv.y;
    o.z = (((p0.z + p1.z) + p2.z) + p3.z) + bv.z;
    o.w = (((p0.w + p1.w) + p2.w) + p3.w) + bv.w;
    *(float4*)(ff + base) = o;
}

// ---- fold(Cp) + b_rec -> memr, then fused fp32 SNN elementwise update ----
__global__ __launch_bounds__(256) void fold_update(
    const float* __restrict__ Cp, const float* __restrict__ b_rec,
    const float* __restrict__ spk_in, const float* __restrict__ ff,
    float* __restrict__ mem, float* __restrict__ ath,
    float* __restrict__ ssum, float* __restrict__ spk_out,
    float* __restrict__ out, int last)
{
    const size_t P = (size_t)B_ROWS * N_OUT;
    size_t base = ((size_t)blockIdx.x * 256 + threadIdx.x) * 4;
    int n = (int)(base & (N_OUT - 1));
    float4 p0 = *(const float4*)(Cp + base);
    float4 p1 = *(const float4*)(Cp + P + base);
    float4 p2 = *(const float4*)(Cp + 2 * P + base);
    float4 p3 = *(const float4*)(Cp + 3 * P + base);
    float4 bv = *(const float4*)(b_rec + n);
    float4 sv = *(const float4*)(spk_in + base);
    float4 av = *(const float4*)(ath + base);
    float4 mv = *(const float4*)(mem + base);
    float4 fv = *(const float4*)(ff + base);
    float4 uv = *(const float4*)(ssum + base);

    float cr[4] = {(((p0.x + p1.x) + p2.x) + p3.x),
                   (((p0.y + p1.y) + p2.y) + p3.y),
                   (((p0.z + p1.z) + p2.z) + p3.z),
                   (((p0.w + p1.w) + p2.w) + p3.w)};
    float ba[4] = {bv.x, bv.y, bv.z, bv.w};
    float sa[4] = {sv.x, sv.y, sv.z, sv.w};
    float aa[4] = {av.x, av.y, av.z, av.w};
    float ma[4] = {mv.x, mv.y, mv.z, mv.w};
    float fa[4] = {fv.x, fv.y, fv.z, fv.w};
    float ua[4] = {uv.x, uv.y, uv.z, uv.w};
    float mo[4], ao[4], uo[4], so[4];
#pragma unroll
    for (int j = 0; j < 4; j++) {
        float memr  = cr[j] + ba[j];      // rounded add
        float sp    = sa[j];
        float t1    = aa[j] * 0.9f;       // rounded
        float t2    = 0.5f * sp;          // exact
        float athn  = t1 + t2;            // rounded
        float u1    = ma[j] * 0.2f;       // rounded
        float u2    = 1.0f - sp;          // exact {1,0,-1}
        float u3    = u1 * u2;            // exact (sign/zero)
        float u4    = u3 + fa[j];         // rounded
        float u5    = athn * 0.2f;        // rounded
        float memff = u4 - u5;            // rounded
        float s_ff  = (memff > 0.5f) ? 1.0f : 0.0f;
        float s_r   = (memr  > 0.5f) ? 1.0f : 0.0f;
        mo[j] = memff + memr;             // rounded
        ao[j] = athn;
        so[j] = s_ff + s_r;               // exact
        uo[j] = ua[j] + so[j];            // exact (small ints)
    }
    *(float4*)(mem + base)     = make_float4(mo[0], mo[1], mo[2], mo[3]);
    *(float4*)(ath + base)     = make_float4(ao[0], ao[1], ao[2], ao[3]);
    *(float4*)(ssum + base)    = make_float4(uo[0], uo[1], uo[2], uo[3]);
    *(float4*)(spk_out + base) = make_float4(so[0], so[1], so[2], so[3]);
    if (last)
        *(float4*)(out + base) = make_float4(uo[0], uo[1], uo[2], uo[3]);
}

extern "C" void kernel_launch(void* const* d_in, const int* in_sizes, int n_in,
                              void* d_out, int out_size, void* d_ws, size_t ws_size,
                              hipStream_t stream) {
    const float* x      = (const float*)d_in[0];
    const float* W_fc   = (const float*)d_in[1];
    const float* b_fc   = (const float*)d_in[2];
    const float* W_rec  = (const float*)d_in[3];
    const float* b_rec  = (const float*)d_in[4];
    const int*   rmask  = (const int*)d_in[5];
    // d_in[6] = spike_window (16)

    char* ws = (char*)d_ws;
    float* WT   = (float*)(ws);                    // 16 MB (fc, then rec)
    float* ff   = (float*)(ws + (16u << 20));      //  4 MB
    float* mem  = (float*)(ws + (20u << 20));      //  4 MB
    float* ath  = (float*)(ws + (24u << 20));      //  4 MB
    float* ssum = (float*)(ws + (28u << 20));      //  4 MB
    float* spkA = (float*)(ws + (32u << 20));      //  4 MB
    float* spkB = (float*)(ws + (36u << 20));      //  4 MB
    float* Cp   = (float*)(ws + (40u << 20));      // 16 MB (total 56 MB)

    dim3 gridT(K_IN / 32, N_OUT / 32);             // (64, 64)
    dim3 blkT(32, 8);
    dim3 gridS((B_ROWS * N_OUT) / 256);            // 4096
    dim3 gridG(N_OUT / BTN, B_ROWS / BTM, NPANEL); // (8, 8, 4) = 256 blocks
    dim3 gridF((B_ROWS * N_OUT) / (256 * 4));      // 1024

    transpose_tile<<<gridT, blkT, 0, stream>>>(W_fc, rmask, WT, 0);
    init_state<<<gridS, 256, 0, stream>>>(mem, ath, ssum, spkA);
    gemm_panel<<<gridG, 256, 0, stream>>>(x, WT, Cp);
    ff_fold<<<gridF, 256, 0, stream>>>(Cp, b_fc, ff);
    transpose_tile<<<gridT, blkT, 0, stream>>>(W_rec, rmask, WT, 1);

    for (int t = 0; t < NSTEP; t++) {
        const float* si = (t & 1) ? spkB : spkA;
        float*       so = (t & 1) ? spkA : spkB;
        gemm_panel<<<gridG, 256, 0, stream>>>(si, WT, Cp);
        fold_update<<<gridF, 256, 0, stream>>>(
            Cp, b_rec, si, ff, mem, ath, ssum, so, (float*)d_out, t == NSTEP - 1);
    }
}

// Round 7
// 1171.668 us; speedup vs baseline: 3.0948x; 1.3133x over previous
//
#include <hip/hip_runtime.h>

// Bit-exact gold model (VERIFIED rounds 12-13, absmax=0): per C element the
// GEMM is 4 panels of 512 sequential fmaf's (k ascending, single acc); panel
// sums folded ((p0+p1)+p2)+p3; then bias add; elementwise = one rounded fp32
// op per ufunc, contract(off).
// Round 21: round-20 structure (broadcast-A LDS, global_load_lds staging,
// 0 conflicts) was latency-bound at 1 wave/SIMD (VALU 38.7%, ~290 cyc/kk vs
// 128 compute; VGPR=88 gave ~1 kk lookahead). Fix: (1) WTM 16->8, BTM 64->32,
// grid (8,16,4)=512 blocks = 2 blocks/CU = 2 waves/SIMD (mutual latency
// hiding); (2) explicit kk+1 register ping-pong prefetch of the 3 ds_reads
// (1 B + 2 uniform A) so reads issue a full kk ahead of use.
// LDS demand 48 B/cyc < 85 ceiling; 36 KB/block x2 = 72 KB/CU.

#pragma clang fp contract(off)

#define B_ROWS 512
#define N_OUT 2048
#define K_IN 2048
#define NSTEP 16
#define NPANEL 4
#define PANK 512
#define BKT 16                 // k per tile
#define BTM 32                 // block m rows (4 waves x 8)
#define BTN 256                // block n cols (64 lanes x 4)
#define WTM 8                  // rows per wave
#define NJ 4                   // cols per lane
#define NTILES (PANK / BKT)    // 32

typedef const __attribute__((address_space(1))) void* gptr_t;
typedef __attribute__((address_space(3))) void* lptr_t;

// ---- 32x32 LDS-tiled transpose: WT[k][n] = W[n][k] (*mask) ----
__global__ __launch_bounds__(256) void transpose_tile(
    const float* __restrict__ W, const int* __restrict__ mask,
    float* __restrict__ WT, int useMask)
{
    __shared__ float t[32][33];
    int kb = blockIdx.x * 32, nb = blockIdx.y * 32;
    int tx = threadIdx.x, ty = threadIdx.y;   // block (32, 8)
#pragma unroll
    for (int r = 0; r < 32; r += 8) {
        size_t src = (size_t)(nb + ty + r) * K_IN + (kb + tx);
        float v = W[src];
        if (useMask) v *= (float)mask[src];   // mask in {0,1}: exact
        t[ty + r][tx] = v;
    }
    __syncthreads();
#pragma unroll
    for (int r = 0; r < 32; r += 8)
        WT[(size_t)(kb + ty + r) * N_OUT + (nb + tx)] = t[tx][ty + r];
}

__global__ __launch_bounds__(256) void init_state(float* mem, float* ath,
                                                  float* ssum, float* spk) {
    int idx = blockIdx.x * 256 + threadIdx.x;
    mem[idx] = 0.0f; ath[idx] = 0.0f; ssum[idx] = 0.0f; spk[idx] = 0.0f;
}

// ---- one K-panel of C = A @ BT : Cp[panel][m][n], bit-exact 512-chain ----
// 4 waves/block. Wave w owns rows m0+w*8..+7 (A broadcast-read: all lanes
// same address). Lane owns cols n0+lane*4..+3 (one b128/kk, conflict-free).
__global__ __launch_bounds__(256, 2) void gemm_panel(
    const float* __restrict__ A,    // [512][2048] (x or spk)
    const float* __restrict__ BT,   // [2048][2048] (WT)
    float* __restrict__ Cp)         // [4][512][2048]
{
    __shared__ float Bs[2][BKT][BTN];   // 32 KB
    __shared__ float As[2][BKT][BTM];   //  4 KB
    const int tid  = threadIdx.x;
    const int w    = tid >> 6;          // wave 0..3
    const int lane = tid & 63;
    const int n0 = blockIdx.x * BTN;
    const int m0 = blockIdx.y * BTM;
    const int pan = blockIdx.z;
    const int kbase = pan * PANK;

    float acc[WTM][NJ];
#pragma unroll
    for (int m = 0; m < WTM; m++)
#pragma unroll
        for (int j = 0; j < NJ; j++) acc[m][j] = 0.0f;

    // stage(buf, kt): per wave 4 B-row DMAs + 2 A-pair DMAs.
    //  B row: 64 lanes x 16 B = 1024 B = one [256n] row (linear LDS dest).
    //  A pair: 64 lanes x 4 B = 256 B = two [32m] rows; lanes 0-31 -> k-row
    //  2j (m=lane), lanes 32-63 -> k-row 2j+1. Per-lane gather of A rows;
    //  per kt the k-range is 64 B = 1 line/row, L1-absorbed re-hits.
    auto stage = [&](int buf, int kt) {
#pragma unroll
        for (int i = 0; i < 4; i++) {
            const int row = w * 4 + i;
            __builtin_amdgcn_global_load_lds(
                (gptr_t)(uintptr_t)(BT + (size_t)(kbase + kt * BKT + row) * N_OUT
                                        + n0 + lane * 4),
                (lptr_t)(uintptr_t)&Bs[buf][row][0], 16, 0, 0);
        }
#pragma unroll
        for (int i = 0; i < 2; i++) {
            const int j = w * 2 + i;          // A-pair index 0..7
            __builtin_amdgcn_global_load_lds(
                (gptr_t)(uintptr_t)(A + (size_t)(m0 + (lane & 31)) * K_IN
                                       + kbase + kt * BKT + 2 * j + (lane >> 5)),
                (lptr_t)(uintptr_t)&As[buf][2 * j][0], 4, 0, 0);
        }
    };

    stage(0, 0);
    for (int kt = 0; kt < NTILES; kt++) {
        const int buf = kt & 1;
        // syncthreads emits s_waitcnt vmcnt(0) lgkmcnt(0) + s_barrier:
        // this wave's DMAs for buf were issued a full kt (~1024+ cyc) ago;
        // barrier => all waves' DMAs done & all finished reading buf^1.
        __syncthreads();
        if (kt + 1 < NTILES) stage(buf ^ 1, kt + 1);  // flies during compute

        // kk-level register ping-pong: reads for kk+1 issue before kk's FMAs.
        float4 bC  = *(const float4*)&Bs[buf][0][lane * 4];
        float4 aC0 = *(const float4*)&As[buf][0][w * WTM];
        float4 aC1 = *(const float4*)&As[buf][0][w * WTM + 4];
#pragma unroll
        for (int kk = 0; kk < BKT; kk++) {
            float4 bN, aN0, aN1;
            if (kk + 1 < BKT) {
                bN  = *(const float4*)&Bs[buf][kk + 1][lane * 4];
                aN0 = *(const float4*)&As[buf][kk + 1][w * WTM];
                aN1 = *(const float4*)&As[buf][kk + 1][w * WTM + 4];
            }
            float a[WTM] = {aC0.x, aC0.y, aC0.z, aC0.w,
                            aC1.x, aC1.y, aC1.z, aC1.w};
            float b[NJ] = {bC.x, bC.y, bC.z, bC.w};
            // kt asc, kk asc, single accumulator => gold 512-chain order
#pragma unroll
            for (int m = 0; m < WTM; m++)
#pragma unroll
                for (int j = 0; j < NJ; j++)
                    acc[m][j] = fmaf(a[m], b[j], acc[m][j]);
            if (kk + 1 < BKT) { bC = bN; aC0 = aN0; aC1 = aN1; }
        }
    }

    const size_t P = (size_t)B_ROWS * N_OUT;
#pragma unroll
    for (int m = 0; m < WTM; m++) {
        size_t off = (size_t)pan * P
                   + (size_t)(m0 + w * WTM + m) * N_OUT + n0 + lane * NJ;
        *(float4*)(Cp + off) = make_float4(acc[m][0], acc[m][1], acc[m][2], acc[m][3]);
    }
}

// ---- ff = fold(Cp) + b_fc  (bit-exact ordered fold) ----
__global__ __launch_bounds__(256) void ff_fold(
    const float* __restrict__ Cp, const float* __restrict__ b_fc,
    float* __restrict__ ff)
{
    const size_t P = (size_t)B_ROWS * N_OUT;
    size_t base = ((size_t)blockIdx.x * 256 + threadIdx.x) * 4;
    int n = (int)(base & (N_OUT - 1));
    float4 p0 = *(const float4*)(Cp + base);
    float4 p1 = *(const float4*)(Cp + P + base);
    float4 p2 = *(const float4*)(Cp + 2 * P + base);
    float4 p3 = *(const float4*)(Cp + 3 * P + base);
    float4 bv = *(const float4*)(b_fc + n);
    float4 o;
    o.x = (((p0.x + p1.x) + p2.x) + p3.x) + bv.x;
    o.y = (((p0.y + p1.y) + p2.y) + p3.y) + bv.y;
    o.z = (((p0.z + p1.z) + p2.z) + p3.z) + bv.z;
    o.w = (((p0.w + p1.w) + p2.w) + p3.w) + bv.w;
    *(float4*)(ff + base) = o;
}

// ---- fold(Cp) + b_rec -> memr, then fused fp32 SNN elementwise update ----
__global__ __launch_bounds__(256) void fold_update(
    const float* __restrict__ Cp, const float* __restrict__ b_rec,
    const float* __restrict__ spk_in, const float* __restrict__ ff,
    float* __restrict__ mem, float* __restrict__ ath,
    float* __restrict__ ssum, float* __restrict__ spk_out,
    float* __restrict__ out, int last)
{
    const size_t P = (size_t)B_ROWS * N_OUT;
    size_t base = ((size_t)blockIdx.x * 256 + threadIdx.x) * 4;
    int n = (int)(base & (N_OUT - 1));
    float4 p0 = *(const float4*)(Cp + base);
    float4 p1 = *(const float4*)(Cp + P + base);
    float4 p2 = *(const float4*)(Cp + 2 * P + base);
    float4 p3 = *(const float4*)(Cp + 3 * P + base);
    float4 bv = *(const float4*)(b_rec + n);
    float4 sv = *(const float4*)(spk_in + base);
    float4 av = *(const float4*)(ath + base);
    float4 mv = *(const float4*)(mem + base);
    float4 fv = *(const float4*)(ff + base);
    float4 uv = *(const float4*)(ssum + base);

    float cr[4] = {(((p0.x + p1.x) + p2.x) + p3.x),
                   (((p0.y + p1.y) + p2.y) + p3.y),
                   (((p0.z + p1.z) + p2.z) + p3.z),
                   (((p0.w + p1.w) + p2.w) + p3.w)};
    float ba[4] = {bv.x, bv.y, bv.z, bv.w};
    float sa[4] = {sv.x, sv.y, sv.z, sv.w};
    float aa[4] = {av.x, av.y, av.z, av.w};
    float ma[4] = {mv.x, mv.y, mv.z, mv.w};
    float fa[4] = {fv.x, fv.y, fv.z, fv.w};
    float ua[4] = {uv.x, uv.y, uv.z, uv.w};
    float mo[4], ao[4], uo[4], so[4];
#pragma unroll
    for (int j = 0; j < 4; j++) {
        float memr  = cr[j] + ba[j];      // rounded add
        float sp    = sa[j];
        float t1    = aa[j] * 0.9f;       // rounded
        float t2    = 0.5f * sp;          // exact
        float athn  = t1 + t2;            // rounded
        float u1    = ma[j] * 0.2f;       // rounded
        float u2    = 1.0f - sp;          // exact {1,0,-1}
        float u3    = u1 * u2;            // exact (sign/zero)
        float u4    = u3 + fa[j];         // rounded
        float u5    = athn * 0.2f;        // rounded
        float memff = u4 - u5;            // rounded
        float s_ff  = (memff > 0.5f) ? 1.0f : 0.0f;
        float s_r   = (memr  > 0.5f) ? 1.0f : 0.0f;
        mo[j] = memff + memr;             // rounded
        ao[j] = athn;
        so[j] = s_ff + s_r;               // exact
        uo[j] = ua[j] + so[j];            // exact (small ints)
    }
    *(float4*)(mem + base)     = make_float4(mo[0], mo[1], mo[2], mo[3]);
    *(float4*)(ath + base)     = make_float4(ao[0], ao[1], ao[2], ao[3]);
    *(float4*)(ssum + base)    = make_float4(uo[0], uo[1], uo[2], uo[3]);
    *(float4*)(spk_out + base) = make_float4(so[0], so[1], so[2], so[3]);
    if (last)
        *(float4*)(out + base) = make_float4(uo[0], uo[1], uo[2], uo[3]);
}

extern "C" void kernel_launch(void* const* d_in, const int* in_sizes, int n_in,
                              void* d_out, int out_size, void* d_ws, size_t ws_size,
                              hipStream_t stream) {
    const float* x      = (const float*)d_in[0];
    const float* W_fc   = (const float*)d_in[1];
    const float* b_fc   = (const float*)d_in[2];
    const float* W_rec  = (const float*)d_in[3];
    const float* b_rec  = (const float*)d_in[4];
    const int*   rmask  = (const int*)d_in[5];
    // d_in[6] = spike_window (16)

    char* ws = (char*)d_ws;
    float* WT   = (float*)(ws);                    // 16 MB (fc, then rec)
    float* ff   = (float*)(ws + (16u << 20));      //  4 MB
    float* mem  = (float*)(ws + (20u << 20));      //  4 MB
    float* ath  = (float*)(ws + (24u << 20));      //  4 MB
    float* ssum = (float*)(ws + (28u << 20));      //  4 MB
    float* spkA = (float*)(ws + (32u << 20));      //  4 MB
    float* spkB = (float*)(ws + (36u << 20));      //  4 MB
    float* Cp   = (float*)(ws + (40u << 20));      // 16 MB (total 56 MB)

    dim3 gridT(K_IN / 32, N_OUT / 32);             // (64, 64)
    dim3 blkT(32, 8);
    dim3 gridS((B_ROWS * N_OUT) / 256);            // 4096
    dim3 gridG(N_OUT / BTN, B_ROWS / BTM, NPANEL); // (8, 16, 4) = 512 blocks
    dim3 gridF((B_ROWS * N_OUT) / (256 * 4));      // 1024

    transpose_tile<<<gridT, blkT, 0, stream>>>(W_fc, rmask, WT, 0);
    init_state<<<gridS, 256, 0, stream>>>(mem, ath, ssum, spkA);
    gemm_panel<<<gridG, 256, 0, stream>>>(x, WT, Cp);
    ff_fold<<<gridF, 256, 0, stream>>>(Cp, b_fc, ff);
    transpose_tile<<<gridT, blkT, 0, stream>>>(W_rec, rmask, WT, 1);

    for (int t = 0; t < NSTEP; t++) {
        const float* si = (t & 1) ? spkB : spkA;
        float*       so = (t & 1) ? spkA : spkB;
        gemm_panel<<<gridG, 256, 0, stream>>>(si, WT, Cp);
        fold_update<<<gridF, 256, 0, stream>>>(
            Cp, b_rec, si, ff, mem, ath, ssum, so, (float*)d_out, t == NSTEP - 1);
    }
}